// Round 1
// baseline (259.726 us; speedup 1.0000x reference)
//
#include <hip/hip_runtime.h>
#include <stdint.h>

typedef unsigned short u16;
typedef unsigned int u32;
typedef __attribute__((ext_vector_type(8))) short s16x8;   // 8 bf16 (4 VGPRs)
typedef __attribute__((ext_vector_type(4))) float fx4;     // 4 fp32 acc

#define AS_GLOBAL __attribute__((address_space(1)))
#define AS_LDS    __attribute__((address_space(3)))

__device__ __forceinline__ void g2l16(const u16* g, u16* l) {
  __builtin_amdgcn_global_load_lds((const AS_GLOBAL unsigned int*)g,
                                   (AS_LDS unsigned int*)l, 16, 0, 0);
}
__device__ __forceinline__ u16 f2bf(float f) {   // fp32 -> bf16 RNE
  u32 u = __float_as_uint(f);
  u += 0x7FFF + ((u >> 16) & 1);
  return (u16)(u >> 16);
}
__device__ __forceinline__ u32 pk2bf(float a, float b) {
  return (u32)f2bf(a) | ((u32)f2bf(b) << 16);
}
// hardware packed fp32->bf16 RNE (1 VOP3 for 2 elements)
__device__ __forceinline__ u32 pkcvt(float a, float b) {
  u32 r;
  asm("v_cvt_pk_bf16_f32 %0, %1, %2" : "=v"(r) : "v"(a), "v"(b));
  return r;
}

// ---------------------------------------------------------------- converts (fused)
__global__ __launch_bounds__(256) void cvt3(const float* __restrict__ a, const float* __restrict__ b,
                                            const float* __restrict__ c, u16* oa, u16* ob, u16* oc, int n4) {
  const float* src = blockIdx.y == 0 ? a : blockIdx.y == 1 ? b : c;
  u16* dst = blockIdx.y == 0 ? oa : blockIdx.y == 1 ? ob : oc;
  int i = blockIdx.x * 256 + threadIdx.x;
  if (i >= n4) return;
  float4 f = ((const float4*)src)[i];
  ushort4 o; o.x = f2bf(f.x); o.y = f2bf(f.y); o.z = f2bf(f.z); o.w = f2bf(f.w);
  ((ushort4*)dst)[i] = o;
}
__global__ __launch_bounds__(256) void cvt4(const float* __restrict__ a, const float* __restrict__ b,
                                            const float* __restrict__ c, const float* __restrict__ d,
                                            u16* oa, u16* ob, u16* oc, u16* od, int n4) {
  const float* src = blockIdx.y == 0 ? a : blockIdx.y == 1 ? b : blockIdx.y == 2 ? c : d;
  u16* dst = blockIdx.y == 0 ? oa : blockIdx.y == 1 ? ob : blockIdx.y == 2 ? oc : od;
  int i = blockIdx.x * 256 + threadIdx.x;
  if (i >= n4) return;
  float4 f = ((const float4*)src)[i];
  ushort4 o; o.x = f2bf(f.x); o.y = f2bf(f.y); o.z = f2bf(f.z); o.w = f2bf(f.w);
  ((ushort4*)dst)[i] = o;
}

// ---------------------------------------------------------------- fused QKV GEMM
__global__ __launch_bounds__(256) void gemm_qkv(
    const u16* __restrict__ Aq, const u16* __restrict__ Ak, const u16* __restrict__ Av,
    const u16* __restrict__ Wq, const u16* __restrict__ Wk, const u16* __restrict__ Wv,
    const float* __restrict__ bq, const float* __restrict__ bk, const float* __restrict__ bv,
    u16* __restrict__ Oq, u16* __restrict__ Ok, u16* __restrict__ Ov)
{
  constexpr int K = 1024;
  __shared__ u16 As[128 * 32];
  __shared__ u16 Bs[128 * 32];
  const int z = blockIdx.z;
  const u16* A = z == 0 ? Aq : z == 1 ? Ak : Av;
  const u16* W = z == 0 ? Wq : z == 1 ? Wk : Wv;
  const float* bias = z == 0 ? bq : z == 1 ? bk : bv;
  u16* outB = z == 0 ? Oq : z == 1 ? Ok : Ov;
  const float scale = z == 0 ? 0.180336880f : 1.0f;  // 0.125 * log2(e)

  const int bm = blockIdx.x, bn = blockIdx.y;
  const int tid = threadIdx.x;
  const int lane = tid & 63, wave = tid >> 6;
  const int quad = lane >> 4, col = lane & 15;
  const int wm = wave >> 1, wn = wave & 1;

  const int L0 = tid, L1 = 256 + tid;
  const int r0 = L0 >> 2, c0 = (L0 & 3) ^ ((r0 >> 1) & 3);
  const int r1 = L1 >> 2, c1 = (L1 & 3) ^ ((r1 >> 1) & 3);
  const u16* gA0 = A + (bm * 128 + r0) * K + c0 * 8;
  const u16* gA1 = A + (bm * 128 + r1) * K + c1 * 8;
  const u16* gB0 = W + (bn * 128 + r0) * K + c0 * 8;
  const u16* gB1 = W + (bn * 128 + r1) * K + c1 * 8;
  u16* lA0 = As + L0 * 8; u16* lA1 = As + L1 * 8;
  u16* lB0 = Bs + L0 * 8; u16* lB1 = Bs + L1 * 8;

  const int aRow = wm * 64 + col;
  const int bRow = wn * 64 + col;

  fx4 zero = {0.f, 0.f, 0.f, 0.f};
  fx4 acc[4][4];
#pragma unroll
  for (int i = 0; i < 4; ++i)
#pragma unroll
    for (int j = 0; j < 4; ++j) acc[i][j] = zero;

  for (int kb = 0; kb < K / 32; ++kb) {
    __syncthreads();
    g2l16(gA0 + kb * 32, lA0);
    g2l16(gA1 + kb * 32, lA1);
    g2l16(gB0 + kb * 32, lB0);
    g2l16(gB1 + kb * 32, lB1);
    __syncthreads();
    s16x8 af[4], bf[4];
#pragma unroll
    for (int mt = 0; mt < 4; ++mt) {
      int row = aRow + mt * 16;
      int ch = row * 4 + (quad ^ ((row >> 1) & 3));
      af[mt] = *(const s16x8*)(As + ch * 8);
    }
#pragma unroll
    for (int nt = 0; nt < 4; ++nt) {
      int row = bRow + nt * 16;
      int ch = row * 4 + (quad ^ ((row >> 1) & 3));
      bf[nt] = *(const s16x8*)(Bs + ch * 8);
    }
#pragma unroll
    for (int mt = 0; mt < 4; ++mt)
#pragma unroll
      for (int nt = 0; nt < 4; ++nt)
        acc[mt][nt] = __builtin_amdgcn_mfma_f32_16x16x32_bf16(af[mt], bf[nt], acc[mt][nt], 0, 0, 0);
  }

#pragma unroll
  for (int nt = 0; nt < 4; ++nt) {
    int n = bn * 128 + wn * 64 + nt * 16 + col;
    float bvv = bias[n];
#pragma unroll
    for (int mt = 0; mt < 4; ++mt) {
      int mbase = bm * 128 + wm * 64 + mt * 16 + quad * 4;
#pragma unroll
      for (int reg = 0; reg < 4; ++reg) {
        int m = mbase + reg;
        float v = (acc[mt][nt][reg] + bvv) * scale;
        int b = m >> 11, s = m & 2047;
        int h = n >> 6, hd = n & 63;
        outB[((b * 16 + h) * 2048 + s) * 64 + hd] = f2bf(v);
      }
    }
  }
}

// ---------------------------------------------------------------- out-proj GEMM (128x64 tile, fp32 out)
__global__ __launch_bounds__(256) void gemm_out(
    const u16* __restrict__ A, const u16* __restrict__ W,
    const float* __restrict__ bias, float* __restrict__ outF)
{
  constexpr int K = 1024;
  __shared__ u16 As[128 * 32];
  __shared__ u16 Bs[64 * 32];
  const int bm = blockIdx.x, bn = blockIdx.y;
  const int tid = threadIdx.x;
  const int lane = tid & 63, wave = tid >> 6;
  const int quad = lane >> 4, col = lane & 15;
  const int wm = wave >> 1, wn = wave & 1;

  const int L0 = tid, L1 = 256 + tid;
  const int r0 = L0 >> 2, c0 = (L0 & 3) ^ ((r0 >> 1) & 3);
  const int r1 = L1 >> 2, c1 = (L1 & 3) ^ ((r1 >> 1) & 3);
  const u16* gA0 = A + (bm * 128 + r0) * K + c0 * 8;
  const u16* gA1 = A + (bm * 128 + r1) * K + c1 * 8;
  const u16* gB0 = W + (bn * 64 + r0) * K + c0 * 8;   // Bs: 256 chunks, 1/thread
  u16* lA0 = As + L0 * 8; u16* lA1 = As + L1 * 8;
  u16* lB0 = Bs + L0 * 8;

  const int aRow = wm * 64 + col;
  const int bRow = wn * 32 + col;

  fx4 zero = {0.f, 0.f, 0.f, 0.f};
  fx4 acc[4][2];
#pragma unroll
  for (int i = 0; i < 4; ++i)
#pragma unroll
    for (int j = 0; j < 2; ++j) acc[i][j] = zero;

  for (int kb = 0; kb < K / 32; ++kb) {
    __syncthreads();
    g2l16(gA0 + kb * 32, lA0);
    g2l16(gA1 + kb * 32, lA1);
    g2l16(gB0 + kb * 32, lB0);
    __syncthreads();
    s16x8 af[4], bf[2];
#pragma unroll
    for (int mt = 0; mt < 4; ++mt) {
      int row = aRow + mt * 16;
      int ch = row * 4 + (quad ^ ((row >> 1) & 3));
      af[mt] = *(const s16x8*)(As + ch * 8);
    }
#pragma unroll
    for (int nt = 0; nt < 2; ++nt) {
      int row = bRow + nt * 16;
      int ch = row * 4 + (quad ^ ((row >> 1) & 3));
      bf[nt] = *(const s16x8*)(Bs + ch * 8);
    }
#pragma unroll
    for (int mt = 0; mt < 4; ++mt)
#pragma unroll
      for (int nt = 0; nt < 2; ++nt)
        acc[mt][nt] = __builtin_amdgcn_mfma_f32_16x16x32_bf16(af[mt], bf[nt], acc[mt][nt], 0, 0, 0);
  }

#pragma unroll
  for (int nt = 0; nt < 2; ++nt) {
    int n = bn * 64 + wn * 32 + nt * 16 + col;
    float bvv = bias[n];
#pragma unroll
    for (int mt = 0; mt < 4; ++mt) {
      int mbase = bm * 128 + wm * 64 + mt * 16 + quad * 4;
#pragma unroll
      for (int reg = 0; reg < 4; ++reg)
        outF[(mbase + reg) * 1024 + n] = acc[mt][nt][reg] + bvv;
    }
  }
}

// ---------------------------------------------------------------- V [bh][s][64] -> Vt [bh][64][s]
__global__ __launch_bounds__(256) void transpose_v(const u16* __restrict__ V,
                                                   u16* __restrict__ Vt) {
  __shared__ u16 tile[64 * 72];
  const int bh = blockIdx.y, s0 = blockIdx.x * 64;
  const int tid = threadIdx.x;
#pragma unroll
  for (int i = 0; i < 2; ++i) {
    int idx = i * 256 + tid;
    int s = idx >> 3, c = idx & 7;
    uint4 v = *(const uint4*)(V + ((size_t)bh * 2048 + s0 + s) * 64 + c * 8);
    const u16* pv = (const u16*)&v;
#pragma unroll
    for (int j = 0; j < 8; ++j) tile[(c * 8 + j) * 72 + s] = pv[j];
  }
  __syncthreads();
#pragma unroll
  for (int i = 0; i < 2; ++i) {
    int idx = i * 256 + tid;
    int d = idx >> 3, c = idx & 7;
    uint4 v = *(const uint4*)(tile + d * 72 + c * 8);
    *(uint4*)(Vt + ((size_t)bh * 64 + d) * 2048 + s0 + c * 8) = v;
  }
}

// ---------------------------------------------------------------- flash attention
// grid (32 qt, 32 bh), 4 waves. Block: 64 q-rows x 128 kv per iter.
// Restructured pipeline (raw barriers, no vmcnt drains):
//   barrier; issue V-tile global_load_lds (pre-swizzled SOURCE, linear LDS dest
//   -> read side's ^col swizzle preserved); QK^T+softmax (consumes K prefetched
//   LAST iter from registers -> its latency hid under prev PV); vmcnt(0) (V
//   landed, hid under QK^T); prefetch next K frags (stay in flight across both
//   barriers); lgkmcnt(0) (P ds_writes); barrier; PV MFMAs (setprio).
// Softmax pack uses v_cvt_pk_bf16_f32 (1 op / 2 elems vs ~10 manual VALU).
__global__ __launch_bounds__(256, 4) void flash_attn(
    const u16* __restrict__ Qp, const u16* __restrict__ Kp,
    const u16* __restrict__ Vt, u16* __restrict__ ctx)
{
  __shared__ u16 sh[16384];  // [0,8192) u16: Vs ; [8192,16384): P (4KB/wave)
  const int qt = blockIdx.x, bh = blockIdx.y;
  const int tid = threadIdx.x, lane = tid & 63, wave = tid >> 6;
  const int quad = lane >> 4, col = lane & 15;
  const int wm = wave >> 1, wn = wave & 1;

  const u16* Qb = Qp + ((size_t)bh * 2048 + qt * 64) * 64;
  const u16* Kb = Kp + (size_t)bh * 2048 * 64;
  const u16* Vb = Vt + (size_t)bh * 64 * 2048;

  s16x8 qf[2][2];   // B-operand: Q[m=lane&15][d=quad*8+j], halves of d=64
#pragma unroll
  for (int mt = 0; mt < 2; ++mt)
#pragma unroll
    for (int h = 0; h < 2; ++h)
      qf[mt][h] = *(const s16x8*)(Qb + (wm * 32 + mt * 16 + col) * 64 + h * 32 + quad * 8);

  fx4 zero = {0.f, 0.f, 0.f, 0.f};
  fx4 acc_o[2][4], acc_l[2];
#pragma unroll
  for (int mt = 0; mt < 2; ++mt) {
    acc_l[mt] = zero;
#pragma unroll
    for (int dt = 0; dt < 4; ++dt) acc_o[mt][dt] = zero;
  }
  s16x8 ones;
#pragma unroll
  for (int j = 0; j < 8; ++j) ones[j] = (short)0x3F80;  // bf16 1.0

  u16* Vs = sh;
  u16* Pw = sh + 8192 + wave * 2048;  // per-wave P[m=32][n=64], 16B-chunk swizzled

  // K fragment double-life registers: loaded one kv-iter ahead.
  s16x8 kf0[4], kf1[4];
  auto loadK = [&](int kvi) {
#pragma unroll
    for (int nt = 0; nt < 4; ++nt) {
      const u16* kr = Kb + (kvi * 128 + wn * 64 + nt * 16 + col) * 64 + quad * 8;
      kf0[nt] = *(const s16x8*)(kr);
      kf1[nt] = *(const s16x8*)(kr + 32);
    }
  };
  loadK(0);

  // V-stage: per-lane PRE-SWIZZLED global source, linear LDS dest (rule-21 pair
  // with the PV read's `^ col`):  phys slot (d, p) holds V^T[d][p ^ (d&15)].
  const u16* vsrc[4];
#pragma unroll
  for (int i = 0; i < 4; ++i) {
    int d = wave * 16 + i * 4 + (lane >> 4);
    int cs = (lane & 15) ^ (d & 15);
    vsrc[i] = Vb + d * 2048 + cs * 8;
  }

  for (int kv = 0; kv < 16; ++kv) {
    const int n0 = kv * 128;
    __builtin_amdgcn_s_barrier();        // prev PV done reading Vs
    // issue async V staging; latency hides under QK^T
#pragma unroll
    for (int i = 0; i < 4; ++i)
      g2l16(vsrc[i] + n0, Vs + (wave * 16 + i * 4) * 128);

    // scores S^T = K*Q^T from prefetched K regs; softmax; P write (b64)
    __builtin_amdgcn_s_setprio(1);
#pragma unroll
    for (int nt = 0; nt < 4; ++nt) {
#pragma unroll
      for (int mt = 0; mt < 2; ++mt) {
        fx4 s = __builtin_amdgcn_mfma_f32_16x16x32_bf16(kf0[nt], qf[mt][0], zero, 0, 0, 0);
        s = __builtin_amdgcn_mfma_f32_16x16x32_bf16(kf1[nt], qf[mt][1], s, 0, 0, 0);
        int m = mt * 16 + col;
        int cch = 2 * nt + (quad >> 1);
        uint2 w;
        w.x = pkcvt(exp2f(s[0]), exp2f(s[1]));
        w.y = pkcvt(exp2f(s[2]), exp2f(s[3]));
        *(uint2*)(Pw + m * 64 + ((cch ^ (m & 7))) * 8 + (quad & 1) * 4) = w;
      }
    }
    __builtin_amdgcn_s_setprio(0);

    // V tile landed (covered by QK^T)
    asm volatile("s_waitcnt vmcnt(0)" ::: "memory");
    // prefetch next K: these 8 loads stay in flight across both barriers,
    // landing during PV + next top-barrier.
    loadK((kv + 1) & 15);
    // P ds_writes complete, then join
    asm volatile("s_waitcnt lgkmcnt(0)" ::: "memory");
    __builtin_amdgcn_s_barrier();        // Vs staged by all + P visible

    // PV: A = P (own wave region), B = V^T rows; l via ones-MFMA
    __builtin_amdgcn_s_setprio(1);
#pragma unroll
    for (int ks = 0; ks < 2; ++ks) {
      s16x8 pf[2];
#pragma unroll
      for (int mt = 0; mt < 2; ++mt)
        pf[mt] = *(const s16x8*)(Pw + (mt * 16 + col) * 64 + ((4 * ks + quad) ^ (col & 7)) * 8);
#pragma unroll
      for (int dt = 0; dt < 4; ++dt) {
        s16x8 vf = *(const s16x8*)(Vs + (dt * 16 + col) * 128 + ((wn * 8 + 4 * ks + quad) ^ col) * 8);
#pragma unroll
        for (int mt = 0; mt < 2; ++mt)
          acc_o[mt][dt] = __builtin_amdgcn_mfma_f32_16x16x32_bf16(pf[mt], vf, acc_o[mt][dt], 0, 0, 0);
      }
#pragma unroll
      for (int mt = 0; mt < 2; ++mt)
        acc_l[mt] = __builtin_amdgcn_mfma_f32_16x16x32_bf16(pf[mt], ones, acc_l[mt], 0, 0, 0);
    }
    __builtin_amdgcn_s_setprio(0);
  }

  // cross-wave (wn) reduction of O,l partials via LDS, then epilogue by wn==0
  __syncthreads();
  float* buf = (float*)sh;
  if (wn == 1) {
#pragma unroll
    for (int mt = 0; mt < 2; ++mt) {
#pragma unroll
      for (int dt = 0; dt < 4; ++dt)
#pragma unroll
        for (int e = 0; e < 4; ++e)
          buf[wm * 2560 + ((mt * 4 + dt) * 4 + e) * 64 + lane] = acc_o[mt][dt][e];
#pragma unroll
      for (int e = 0; e < 4; ++e)
        buf[wm * 2560 + (32 + mt * 4 + e) * 64 + lane] = acc_l[mt][e];
    }
  }
  __syncthreads();
  if (wn == 0) {
    const int b = bh >> 4, h = bh & 15;
#pragma unroll
    for (int mt = 0; mt < 2; ++mt) {
      fx4 rl;
#pragma unroll
      for (int e = 0; e < 4; ++e) {
        float l = acc_l[mt][e] + buf[wm * 2560 + (32 + mt * 4 + e) * 64 + lane];
        rl[e] = 1.0f / l;
      }
#pragma unroll
      for (int dt = 0; dt < 4; ++dt)
#pragma unroll
        for (int e = 0; e < 4; ++e) {
          float v = (acc_o[mt][dt][e] + buf[wm * 2560 + ((mt * 4 + dt) * 4 + e) * 64 + lane]) * rl[e];
          int s = qt * 64 + wm * 32 + mt * 16 + quad * 4 + e;
          ctx[((size_t)(b * 2048 + s)) * 1024 + h * 64 + dt * 16 + col] = f2bf(v);
        }
    }
  }
}

// ---------------------------------------------------------------- launch
extern "C" void kernel_launch(void* const* d_in, const int* in_sizes, int n_in,
                              void* d_out, int out_size, void* d_ws, size_t ws_size,
                              hipStream_t stream) {
  const float* q  = (const float*)d_in[0];
  const float* k  = (const float*)d_in[1];
  const float* v  = (const float*)d_in[2];
  const float* Wq = (const float*)d_in[3];
  const float* bq = (const float*)d_in[4];
  const float* Wk = (const float*)d_in[5];
  const float* bk = (const float*)d_in[6];
  const float* Wv = (const float*)d_in[7];
  const float* bv = (const float*)d_in[8];
  const float* Wo = (const float*)d_in[9];
  const float* bo = (const float*)d_in[10];
  float* out = (float*)d_out;

  char* ws = (char*)d_ws;
  const size_t MB = 1u << 20;
  u16* qb  = (u16*)(ws + 0 * MB);
  u16* kb  = (u16*)(ws + 8 * MB);
  u16* vb  = (u16*)(ws + 16 * MB);
  u16* wqb = (u16*)(ws + 24 * MB);
  u16* wkb = (u16*)(ws + 26 * MB);
  u16* wvb = (u16*)(ws + 28 * MB);
  u16* wob = (u16*)(ws + 30 * MB);
  u16* Qp  = (u16*)(ws + 32 * MB);
  u16* Kp  = (u16*)(ws + 40 * MB);
  u16* Vp  = (u16*)(ws + 48 * MB);
  u16* Vtp = (u16*)(ws + 56 * MB);
  u16* ctx = (u16*)(ws + 64 * MB);   // total 72 MB

  cvt3<<<dim3(4096, 3), 256, 0, stream>>>(q, k, v, qb, kb, vb, 1048576);
  cvt4<<<dim3(1024, 4), 256, 0, stream>>>(Wq, Wk, Wv, Wo, wqb, wkb, wvb, wob, 262144);

  gemm_qkv<<<dim3(32, 8, 3), 256, 0, stream>>>(qb, kb, vb, wqb, wkb, wvb,
                                               bq, bk, bv, Qp, Kp, Vp);
  transpose_v<<<dim3(32, 32), 256, 0, stream>>>(Vp, Vtp);
  flash_attn<<<dim3(32, 32), 256, 0, stream>>>(Qp, Kp, Vtp, ctx);
  gemm_out<<<dim3(32, 16), 256, 0, stream>>>(ctx, wob, bo, out);
}

// Round 5
// 255.285 us; speedup vs baseline: 1.0174x; 1.0174x over previous
//
#include <hip/hip_runtime.h>
#include <stdint.h>

typedef unsigned short u16;
typedef unsigned int u32;
typedef __attribute__((ext_vector_type(8))) short s16x8;   // 8 bf16 (4 VGPRs)
typedef __attribute__((ext_vector_type(4))) float fx4;     // 4 fp32 acc

#define AS_GLOBAL __attribute__((address_space(1)))
#define AS_LDS    __attribute__((address_space(3)))

__device__ __forceinline__ void g2l16(const u16* g, u16* l) {
  __builtin_amdgcn_global_load_lds((const AS_GLOBAL unsigned int*)g,
                                   (AS_LDS unsigned int*)l, 16, 0, 0);
}
__device__ __forceinline__ u16 f2bf(float f) {   // fp32 -> bf16 RNE
  u32 u = __float_as_uint(f);
  u += 0x7FFF + ((u >> 16) & 1);
  return (u16)(u >> 16);
}
// hardware packed fp32->bf16 RNE (1 VOP3 for 2 elements)
__device__ __forceinline__ u32 pkcvt(float a, float b) {
  u32 r;
  asm("v_cvt_pk_bf16_f32 %0, %1, %2" : "=v"(r) : "v"(a), "v"(b));
  return r;
}

// ---------------------------------------------------------------- converts (fused)
__global__ __launch_bounds__(256) void cvt3(const float* __restrict__ a, const float* __restrict__ b,
                                            const float* __restrict__ c, u16* oa, u16* ob, u16* oc, int n4) {
  const float* src = blockIdx.y == 0 ? a : blockIdx.y == 1 ? b : c;
  u16* dst = blockIdx.y == 0 ? oa : blockIdx.y == 1 ? ob : oc;
  int i = blockIdx.x * 256 + threadIdx.x;
  if (i >= n4) return;
  float4 f = ((const float4*)src)[i];
  ushort4 o; o.x = f2bf(f.x); o.y = f2bf(f.y); o.z = f2bf(f.z); o.w = f2bf(f.w);
  ((ushort4*)dst)[i] = o;
}
__global__ __launch_bounds__(256) void cvt4(const float* __restrict__ a, const float* __restrict__ b,
                                            const float* __restrict__ c, const float* __restrict__ d,
                                            u16* oa, u16* ob, u16* oc, u16* od, int n4) {
  const float* src = blockIdx.y == 0 ? a : blockIdx.y == 1 ? b : blockIdx.y == 2 ? c : d;
  u16* dst = blockIdx.y == 0 ? oa : blockIdx.y == 1 ? ob : blockIdx.y == 2 ? oc : od;
  int i = blockIdx.x * 256 + threadIdx.x;
  if (i >= n4) return;
  float4 f = ((const float4*)src)[i];
  ushort4 o; o.x = f2bf(f.x); o.y = f2bf(f.y); o.z = f2bf(f.z); o.w = f2bf(f.w);
  ((ushort4*)dst)[i] = o;
}

// ---------------------------------------------------------------- fused QKV GEMM
// z==0 (Q): scaled by sm_scale*log2e, layout [B,H,S,Hd].
// z==1 (K): layout [B,H,S,Hd].
// z==2 (V): written DIRECTLY as V^T [B,H,Hd,S] (transpose_v kernel eliminated).
// The (m,n) -> memory mapping is identical to the verified z<=1 epilogue;
// the 4 acc regs of a tile are 4 consecutive s at fixed (h,hd) -> packed 8B store.
__global__ __launch_bounds__(256) void gemm_qkv(
    const u16* __restrict__ Aq, const u16* __restrict__ Ak, const u16* __restrict__ Av,
    const u16* __restrict__ Wq, const u16* __restrict__ Wk, const u16* __restrict__ Wv,
    const float* __restrict__ bq, const float* __restrict__ bk, const float* __restrict__ bv,
    u16* __restrict__ Oq, u16* __restrict__ Ok, u16* __restrict__ Ovt)
{
  constexpr int K = 1024;
  __shared__ u16 As[128 * 32];
  __shared__ u16 Bs[128 * 32];
  const int z = blockIdx.z;
  const u16* A = z == 0 ? Aq : z == 1 ? Ak : Av;
  const u16* W = z == 0 ? Wq : z == 1 ? Wk : Wv;
  const float* bias = z == 0 ? bq : z == 1 ? bk : bv;
  const float scale = z == 0 ? 0.180336880f : 1.0f;  // 0.125 * log2(e)

  const int bm = blockIdx.x, bn = blockIdx.y;
  const int tid = threadIdx.x;
  const int lane = tid & 63, wave = tid >> 6;
  const int quad = lane >> 4, col = lane & 15;
  const int wm = wave >> 1, wn = wave & 1;

  const int L0 = tid, L1 = 256 + tid;
  const int r0 = L0 >> 2, c0 = (L0 & 3) ^ ((r0 >> 1) & 3);
  const int r1 = L1 >> 2, c1 = (L1 & 3) ^ ((r1 >> 1) & 3);
  const u16* gA0 = A + (bm * 128 + r0) * K + c0 * 8;
  const u16* gA1 = A + (bm * 128 + r1) * K + c1 * 8;
  const u16* gB0 = W + (bn * 128 + r0) * K + c0 * 8;
  const u16* gB1 = W + (bn * 128 + r1) * K + c1 * 8;
  u16* lA0 = As + L0 * 8; u16* lA1 = As + L1 * 8;
  u16* lB0 = Bs + L0 * 8; u16* lB1 = Bs + L1 * 8;

  const int aRow = wm * 64 + col;
  const int bRow = wn * 64 + col;

  fx4 zero = {0.f, 0.f, 0.f, 0.f};
  fx4 acc[4][4];
#pragma unroll
  for (int i = 0; i < 4; ++i)
#pragma unroll
    for (int j = 0; j < 4; ++j) acc[i][j] = zero;

  for (int kb = 0; kb < K / 32; ++kb) {
    __syncthreads();
    g2l16(gA0 + kb * 32, lA0);
    g2l16(gA1 + kb * 32, lA1);
    g2l16(gB0 + kb * 32, lB0);
    g2l16(gB1 + kb * 32, lB1);
    __syncthreads();
    s16x8 af[4], bf[4];
#pragma unroll
    for (int mt = 0; mt < 4; ++mt) {
      int row = aRow + mt * 16;
      int ch = row * 4 + (quad ^ ((row >> 1) & 3));
      af[mt] = *(const s16x8*)(As + ch * 8);
    }
#pragma unroll
    for (int nt = 0; nt < 4; ++nt) {
      int row = bRow + nt * 16;
      int ch = row * 4 + (quad ^ ((row >> 1) & 3));
      bf[nt] = *(const s16x8*)(Bs + ch * 8);
    }
#pragma unroll
    for (int mt = 0; mt < 4; ++mt)
#pragma unroll
      for (int nt = 0; nt < 4; ++nt)
        acc[mt][nt] = __builtin_amdgcn_mfma_f32_16x16x32_bf16(af[mt], bf[nt], acc[mt][nt], 0, 0, 0);
  }

  if (z == 2) {
    // direct V^T store: per (mt,nt) the 4 acc regs are 4 CONSECUTIVE s values
    // at fixed (h,hd) -> one packed 8B store. Vt[((b*16+h)*64+hd)*2048 + s].
#pragma unroll
    for (int nt = 0; nt < 4; ++nt) {
      int n = bn * 128 + wn * 64 + nt * 16 + col;
      float bvv = bias[n];
      int h = n >> 6, hd = n & 63;
#pragma unroll
      for (int mt = 0; mt < 4; ++mt) {
        int mbase = bm * 128 + wm * 64 + mt * 16 + quad * 4;
        int b = mbase >> 11, s = mbase & 2047;
        uint2 w;
        w.x = pkcvt(acc[mt][nt][0] + bvv, acc[mt][nt][1] + bvv);
        w.y = pkcvt(acc[mt][nt][2] + bvv, acc[mt][nt][3] + bvv);
        *(uint2*)(Ovt + ((size_t)((b * 16 + h) * 64 + hd)) * 2048 + s) = w;
      }
    }
  } else {
    u16* outB = z == 0 ? Oq : Ok;
#pragma unroll
    for (int nt = 0; nt < 4; ++nt) {
      int n = bn * 128 + wn * 64 + nt * 16 + col;
      float bvv = bias[n];
#pragma unroll
      for (int mt = 0; mt < 4; ++mt) {
        int mbase = bm * 128 + wm * 64 + mt * 16 + quad * 4;
#pragma unroll
        for (int reg = 0; reg < 4; ++reg) {
          int m = mbase + reg;
          float v = (acc[mt][nt][reg] + bvv) * scale;
          int b = m >> 11, s = m & 2047;
          int h = n >> 6, hd = n & 63;
          outB[((b * 16 + h) * 2048 + s) * 64 + hd] = f2bf(v);
        }
      }
    }
  }
}

// ---------------------------------------------------------------- out-proj GEMM (128x64 tile, fp32 out)
__global__ __launch_bounds__(256) void gemm_out(
    const u16* __restrict__ A, const u16* __restrict__ W,
    const float* __restrict__ bias, float* __restrict__ outF)
{
  constexpr int K = 1024;
  __shared__ u16 As[128 * 32];
  __shared__ u16 Bs[64 * 32];
  const int bm = blockIdx.x, bn = blockIdx.y;
  const int tid = threadIdx.x;
  const int lane = tid & 63, wave = tid >> 6;
  const int quad = lane >> 4, col = lane & 15;
  const int wm = wave >> 1, wn = wave & 1;

  const int L0 = tid, L1 = 256 + tid;
  const int r0 = L0 >> 2, c0 = (L0 & 3) ^ ((r0 >> 1) & 3);
  const int r1 = L1 >> 2, c1 = (L1 & 3) ^ ((r1 >> 1) & 3);
  const u16* gA0 = A + (bm * 128 + r0) * K + c0 * 8;
  const u16* gA1 = A + (bm * 128 + r1) * K + c1 * 8;
  const u16* gB0 = W + (bn * 64 + r0) * K + c0 * 8;   // Bs: 256 chunks, 1/thread
  u16* lA0 = As + L0 * 8; u16* lA1 = As + L1 * 8;
  u16* lB0 = Bs + L0 * 8;

  const int aRow = wm * 64 + col;
  const int bRow = wn * 32 + col;

  fx4 zero = {0.f, 0.f, 0.f, 0.f};
  fx4 acc[4][2];
#pragma unroll
  for (int i = 0; i < 4; ++i)
#pragma unroll
    for (int j = 0; j < 2; ++j) acc[i][j] = zero;

  for (int kb = 0; kb < K / 32; ++kb) {
    __syncthreads();
    g2l16(gA0 + kb * 32, lA0);
    g2l16(gA1 + kb * 32, lA1);
    g2l16(gB0 + kb * 32, lB0);
    __syncthreads();
    s16x8 af[4], bf[2];
#pragma unroll
    for (int mt = 0; mt < 4; ++mt) {
      int row = aRow + mt * 16;
      int ch = row * 4 + (quad ^ ((row >> 1) & 3));
      af[mt] = *(const s16x8*)(As + ch * 8);
    }
#pragma unroll
    for (int nt = 0; nt < 2; ++nt) {
      int row = bRow + nt * 16;
      int ch = row * 4 + (quad ^ ((row >> 1) & 3));
      bf[nt] = *(const s16x8*)(Bs + ch * 8);
    }
#pragma unroll
    for (int mt = 0; mt < 4; ++mt)
#pragma unroll
      for (int nt = 0; nt < 2; ++nt)
        acc[mt][nt] = __builtin_amdgcn_mfma_f32_16x16x32_bf16(af[mt], bf[nt], acc[mt][nt], 0, 0, 0);
  }

#pragma unroll
  for (int nt = 0; nt < 2; ++nt) {
    int n = bn * 64 + wn * 32 + nt * 16 + col;
    float bvv = bias[n];
#pragma unroll
    for (int mt = 0; mt < 4; ++mt) {
      int mbase = bm * 128 + wm * 64 + mt * 16 + quad * 4;
#pragma unroll
      for (int reg = 0; reg < 4; ++reg)
        outF[(mbase + reg) * 1024 + n] = acc[mt][nt][reg] + bvv;
    }
  }
}

// ---------------------------------------------------------------- flash attention
// grid (32 qt, 32 bh), 4 waves. Block: 64 q-rows x 128 kv per iter.
// (round-1 structure, verbatim — last passing version)
//   barrier; issue V-tile global_load_lds (pre-swizzled SOURCE, linear LDS dest
//   -> read side's ^col swizzle preserved); QK^T+softmax (consumes K prefetched
//   LAST iter from registers); vmcnt(0) (V landed, hid under QK^T); prefetch
//   next K frags; lgkmcnt(0) (P ds_writes); barrier; PV MFMAs (setprio).
__global__ __launch_bounds__(256, 4) void flash_attn(
    const u16* __restrict__ Qp, const u16* __restrict__ Kp,
    const u16* __restrict__ Vt, u16* __restrict__ ctx)
{
  __shared__ u16 sh[16384];  // [0,8192) u16: Vs ; [8192,16384): P (4KB/wave)
  const int qt = blockIdx.x, bh = blockIdx.y;
  const int tid = threadIdx.x, lane = tid & 63, wave = tid >> 6;
  const int quad = lane >> 4, col = lane & 15;
  const int wm = wave >> 1, wn = wave & 1;

  const u16* Qb = Qp + ((size_t)bh * 2048 + qt * 64) * 64;
  const u16* Kb = Kp + (size_t)bh * 2048 * 64;
  const u16* Vb = Vt + (size_t)bh * 64 * 2048;

  s16x8 qf[2][2];   // B-operand: Q[m=lane&15][d=quad*8+j], halves of d=64
#pragma unroll
  for (int mt = 0; mt < 2; ++mt)
#pragma unroll
    for (int h = 0; h < 2; ++h)
      qf[mt][h] = *(const s16x8*)(Qb + (wm * 32 + mt * 16 + col) * 64 + h * 32 + quad * 8);

  fx4 zero = {0.f, 0.f, 0.f, 0.f};
  fx4 acc_o[2][4], acc_l[2];
#pragma unroll
  for (int mt = 0; mt < 2; ++mt) {
    acc_l[mt] = zero;
#pragma unroll
    for (int dt = 0; dt < 4; ++dt) acc_o[mt][dt] = zero;
  }
  s16x8 ones;
#pragma unroll
  for (int j = 0; j < 8; ++j) ones[j] = (short)0x3F80;  // bf16 1.0

  u16* Vs = sh;
  u16* Pw = sh + 8192 + wave * 2048;  // per-wave P[m=32][n=64], 16B-chunk swizzled

  // K fragment double-life registers: loaded one kv-iter ahead.
  s16x8 kf0[4], kf1[4];
  auto loadK = [&](int kvi) {
#pragma unroll
    for (int nt = 0; nt < 4; ++nt) {
      const u16* kr = Kb + (kvi * 128 + wn * 64 + nt * 16 + col) * 64 + quad * 8;
      kf0[nt] = *(const s16x8*)(kr);
      kf1[nt] = *(const s16x8*)(kr + 32);
    }
  };
  loadK(0);

  // V-stage: per-lane PRE-SWIZZLED global source, linear LDS dest (rule-21 pair
  // with the PV read's `^ col`):  phys slot (d, p) holds V^T[d][p ^ (d&15)].
  const u16* vsrc[4];
#pragma unroll
  for (int i = 0; i < 4; ++i) {
    int d = wave * 16 + i * 4 + (lane >> 4);
    int cs = (lane & 15) ^ (d & 15);
    vsrc[i] = Vb + d * 2048 + cs * 8;
  }

  for (int kv = 0; kv < 16; ++kv) {
    const int n0 = kv * 128;
    __builtin_amdgcn_s_barrier();        // prev PV done reading Vs
    // issue async V staging; latency hides under QK^T
#pragma unroll
    for (int i = 0; i < 4; ++i)
      g2l16(vsrc[i] + n0, Vs + (wave * 16 + i * 4) * 128);

    // scores S^T = K*Q^T from prefetched K regs; softmax; P write (b64)
    __builtin_amdgcn_s_setprio(1);
#pragma unroll
    for (int nt = 0; nt < 4; ++nt) {
#pragma unroll
      for (int mt = 0; mt < 2; ++mt) {
        fx4 s = __builtin_amdgcn_mfma_f32_16x16x32_bf16(kf0[nt], qf[mt][0], zero, 0, 0, 0);
        s = __builtin_amdgcn_mfma_f32_16x16x32_bf16(kf1[nt], qf[mt][1], s, 0, 0, 0);
        int m = mt * 16 + col;
        int cch = 2 * nt + (quad >> 1);
        uint2 w;
        w.x = pkcvt(exp2f(s[0]), exp2f(s[1]));
        w.y = pkcvt(exp2f(s[2]), exp2f(s[3]));
        *(uint2*)(Pw + m * 64 + ((cch ^ (m & 7))) * 8 + (quad & 1) * 4) = w;
      }
    }
    __builtin_amdgcn_s_setprio(0);

    // V tile landed (covered by QK^T)
    asm volatile("s_waitcnt vmcnt(0)" ::: "memory");
    // prefetch next K
    loadK((kv + 1) & 15);
    // P ds_writes complete, then join
    asm volatile("s_waitcnt lgkmcnt(0)" ::: "memory");
    __builtin_amdgcn_s_barrier();        // Vs staged by all + P visible

    // PV: A = P (own wave region), B = V^T rows; l via ones-MFMA
    __builtin_amdgcn_s_setprio(1);
#pragma unroll
    for (int ks = 0; ks < 2; ++ks) {
      s16x8 pf[2];
#pragma unroll
      for (int mt = 0; mt < 2; ++mt)
        pf[mt] = *(const s16x8*)(Pw + (mt * 16 + col) * 64 + ((4 * ks + quad) ^ (col & 7)) * 8);
#pragma unroll
      for (int dt = 0; dt < 4; ++dt) {
        s16x8 vf = *(const s16x8*)(Vs + (dt * 16 + col) * 128 + ((wn * 8 + 4 * ks + quad) ^ col) * 8);
#pragma unroll
        for (int mt = 0; mt < 2; ++mt)
          acc_o[mt][dt] = __builtin_amdgcn_mfma_f32_16x16x32_bf16(pf[mt], vf, acc_o[mt][dt], 0, 0, 0);
      }
#pragma unroll
      for (int mt = 0; mt < 2; ++mt)
        acc_l[mt] = __builtin_amdgcn_mfma_f32_16x16x32_bf16(pf[mt], ones, acc_l[mt], 0, 0, 0);
    }
    __builtin_amdgcn_s_setprio(0);
  }

  // cross-wave (wn) reduction of O,l partials via LDS, then epilogue by wn==0
  __syncthreads();
  float* buf = (float*)sh;
  if (wn == 1) {
#pragma unroll
    for (int mt = 0; mt < 2; ++mt) {
#pragma unroll
      for (int dt = 0; dt < 4; ++dt)
#pragma unroll
        for (int e = 0; e < 4; ++e)
          buf[wm * 2560 + ((mt * 4 + dt) * 4 + e) * 64 + lane] = acc_o[mt][dt][e];
#pragma unroll
      for (int e = 0; e < 4; ++e)
        buf[wm * 2560 + (32 + mt * 4 + e) * 64 + lane] = acc_l[mt][e];
    }
  }
  __syncthreads();
  if (wn == 0) {
    const int b = bh >> 4, h = bh & 15;
#pragma unroll
    for (int mt = 0; mt < 2; ++mt) {
      fx4 rl;
#pragma unroll
      for (int e = 0; e < 4; ++e) {
        float l = acc_l[mt][e] + buf[wm * 2560 + (32 + mt * 4 + e) * 64 + lane];
        rl[e] = 1.0f / l;
      }
#pragma unroll
      for (int dt = 0; dt < 4; ++dt)
#pragma unroll
        for (int e = 0; e < 4; ++e) {
          float v = (acc_o[mt][dt][e] + buf[wm * 2560 + ((mt * 4 + dt) * 4 + e) * 64 + lane]) * rl[e];
          int s = qt * 64 + wm * 32 + mt * 16 + quad * 4 + e;
          ctx[((size_t)(b * 2048 + s)) * 1024 + h * 64 + dt * 16 + col] = f2bf(v);
        }
    }
  }
}

// ---------------------------------------------------------------- launch
extern "C" void kernel_launch(void* const* d_in, const int* in_sizes, int n_in,
                              void* d_out, int out_size, void* d_ws, size_t ws_size,
                              hipStream_t stream) {
  const float* q  = (const float*)d_in[0];
  const float* k  = (const float*)d_in[1];
  const float* v  = (const float*)d_in[2];
  const float* Wq = (const float*)d_in[3];
  const float* bq = (const float*)d_in[4];
  const float* Wk = (const float*)d_in[5];
  const float* bk = (const float*)d_in[6];
  const float* Wv = (const float*)d_in[7];
  const float* bv = (const float*)d_in[8];
  const float* Wo = (const float*)d_in[9];
  const float* bo = (const float*)d_in[10];
  float* out = (float*)d_out;

  char* ws = (char*)d_ws;
  const size_t MB = 1u << 20;
  u16* qb  = (u16*)(ws + 0 * MB);
  u16* kb  = (u16*)(ws + 8 * MB);
  u16* vb  = (u16*)(ws + 16 * MB);
  u16* wqb = (u16*)(ws + 24 * MB);
  u16* wkb = (u16*)(ws + 26 * MB);
  u16* wvb = (u16*)(ws + 28 * MB);
  u16* wob = (u16*)(ws + 30 * MB);
  u16* Qp  = (u16*)(ws + 32 * MB);
  u16* Kp  = (u16*)(ws + 40 * MB);
  u16* Vtp = (u16*)(ws + 56 * MB);
  u16* ctx = (u16*)(ws + 64 * MB);   // total 72 MB

  cvt3<<<dim3(4096, 3), 256, 0, stream>>>(q, k, v, qb, kb, vb, 1048576);
  cvt4<<<dim3(1024, 4), 256, 0, stream>>>(Wq, Wk, Wv, Wo, wqb, wkb, wvb, wob, 262144);

  gemm_qkv<<<dim3(32, 8, 3), 256, 0, stream>>>(qb, kb, vb, wqb, wkb, wvb,
                                               bq, bk, bv, Qp, Kp, Vtp);
  flash_attn<<<dim3(32, 32), 256, 0, stream>>>(Qp, Kp, Vtp, ctx);
  gemm_out<<<dim3(32, 16), 256, 0, stream>>>(ctx, wob, bo, out);
}

// Round 7
// 232.652 us; speedup vs baseline: 1.1164x; 1.0973x over previous
//
#include <hip/hip_runtime.h>
#include <stdint.h>

typedef unsigned short u16;
typedef unsigned int u32;
typedef __attribute__((ext_vector_type(8))) short s16x8;   // 8 bf16 (4 VGPRs)
typedef __attribute__((ext_vector_type(4))) float fx4;     // 4 fp32 acc

#define AS_GLOBAL __attribute__((address_space(1)))
#define AS_LDS    __attribute__((address_space(3)))

__device__ __forceinline__ void g2l16(const u16* g, u16* l) {
  __builtin_amdgcn_global_load_lds((const AS_GLOBAL unsigned int*)g,
                                   (AS_LDS unsigned int*)l, 16, 0, 0);
}
__device__ __forceinline__ u16 f2bf(float f) {   // fp32 -> bf16 RNE
  u32 u = __float_as_uint(f);
  u += 0x7FFF + ((u >> 16) & 1);
  return (u16)(u >> 16);
}
// hardware packed fp32->bf16 RNE (1 VOP3 for 2 elements)
__device__ __forceinline__ u32 pkcvt(float a, float b) {
  u32 r;
  asm("v_cvt_pk_bf16_f32 %0, %1, %2" : "=v"(r) : "v"(a), "v"(b));
  return r;
}

// ---------------------------------------------------------------- converts (fused)
__global__ __launch_bounds__(256) void cvt3(const float* __restrict__ a, const float* __restrict__ b,
                                            const float* __restrict__ c, u16* oa, u16* ob, u16* oc, int n4) {
  const float* src = blockIdx.y == 0 ? a : blockIdx.y == 1 ? b : c;
  u16* dst = blockIdx.y == 0 ? oa : blockIdx.y == 1 ? ob : oc;
  int i = blockIdx.x * 256 + threadIdx.x;
  if (i >= n4) return;
  float4 f = ((const float4*)src)[i];
  ushort4 o; o.x = f2bf(f.x); o.y = f2bf(f.y); o.z = f2bf(f.z); o.w = f2bf(f.w);
  ((ushort4*)dst)[i] = o;
}
__global__ __launch_bounds__(256) void cvt4(const float* __restrict__ a, const float* __restrict__ b,
                                            const float* __restrict__ c, const float* __restrict__ d,
                                            u16* oa, u16* ob, u16* oc, u16* od, int n4) {
  const float* src = blockIdx.y == 0 ? a : blockIdx.y == 1 ? b : blockIdx.y == 2 ? c : d;
  u16* dst = blockIdx.y == 0 ? oa : blockIdx.y == 1 ? ob : blockIdx.y == 2 ? oc : od;
  int i = blockIdx.x * 256 + threadIdx.x;
  if (i >= n4) return;
  float4 f = ((const float4*)src)[i];
  ushort4 o; o.x = f2bf(f.x); o.y = f2bf(f.y); o.z = f2bf(f.z); o.w = f2bf(f.w);
  ((ushort4*)dst)[i] = o;
}

// ---------------------------------------------------------------- fused QKV GEMM
// z==0 (Q): scaled by sm_scale*log2e, layout [B,H,S,Hd].
// z==1 (K): layout [B,H,S,Hd].
// z==2 (V): written DIRECTLY as V^T [B,H,Hd,S] (transpose_v kernel eliminated).
__global__ __launch_bounds__(256) void gemm_qkv(
    const u16* __restrict__ Aq, const u16* __restrict__ Ak, const u16* __restrict__ Av,
    const u16* __restrict__ Wq, const u16* __restrict__ Wk, const u16* __restrict__ Wv,
    const float* __restrict__ bq, const float* __restrict__ bk, const float* __restrict__ bv,
    u16* __restrict__ Oq, u16* __restrict__ Ok, u16* __restrict__ Ovt)
{
  constexpr int K = 1024;
  __shared__ u16 As[128 * 32];
  __shared__ u16 Bs[128 * 32];
  const int z = blockIdx.z;
  const u16* A = z == 0 ? Aq : z == 1 ? Ak : Av;
  const u16* W = z == 0 ? Wq : z == 1 ? Wk : Wv;
  const float* bias = z == 0 ? bq : z == 1 ? bk : bv;
  const float scale = z == 0 ? 0.180336880f : 1.0f;  // 0.125 * log2(e)

  const int bm = blockIdx.x, bn = blockIdx.y;
  const int tid = threadIdx.x;
  const int lane = tid & 63, wave = tid >> 6;
  const int quad = lane >> 4, col = lane & 15;
  const int wm = wave >> 1, wn = wave & 1;

  const int L0 = tid, L1 = 256 + tid;
  const int r0 = L0 >> 2, c0 = (L0 & 3) ^ ((r0 >> 1) & 3);
  const int r1 = L1 >> 2, c1 = (L1 & 3) ^ ((r1 >> 1) & 3);
  const u16* gA0 = A + (bm * 128 + r0) * K + c0 * 8;
  const u16* gA1 = A + (bm * 128 + r1) * K + c1 * 8;
  const u16* gB0 = W + (bn * 128 + r0) * K + c0 * 8;
  const u16* gB1 = W + (bn * 128 + r1) * K + c1 * 8;
  u16* lA0 = As + L0 * 8; u16* lA1 = As + L1 * 8;
  u16* lB0 = Bs + L0 * 8; u16* lB1 = Bs + L1 * 8;

  const int aRow = wm * 64 + col;
  const int bRow = wn * 64 + col;

  fx4 zero = {0.f, 0.f, 0.f, 0.f};
  fx4 acc[4][4];
#pragma unroll
  for (int i = 0; i < 4; ++i)
#pragma unroll
    for (int j = 0; j < 4; ++j) acc[i][j] = zero;

  for (int kb = 0; kb < K / 32; ++kb) {
    __syncthreads();
    g2l16(gA0 + kb * 32, lA0);
    g2l16(gA1 + kb * 32, lA1);
    g2l16(gB0 + kb * 32, lB0);
    g2l16(gB1 + kb * 32, lB1);
    __syncthreads();
    s16x8 af[4], bf[4];
#pragma unroll
    for (int mt = 0; mt < 4; ++mt) {
      int row = aRow + mt * 16;
      int ch = row * 4 + (quad ^ ((row >> 1) & 3));
      af[mt] = *(const s16x8*)(As + ch * 8);
    }
#pragma unroll
    for (int nt = 0; nt < 4; ++nt) {
      int row = bRow + nt * 16;
      int ch = row * 4 + (quad ^ ((row >> 1) & 3));
      bf[nt] = *(const s16x8*)(Bs + ch * 8);
    }
#pragma unroll
    for (int mt = 0; mt < 4; ++mt)
#pragma unroll
      for (int nt = 0; nt < 4; ++nt)
        acc[mt][nt] = __builtin_amdgcn_mfma_f32_16x16x32_bf16(af[mt], bf[nt], acc[mt][nt], 0, 0, 0);
  }

  if (z == 2) {
    // direct V^T store: per (mt,nt) the 4 acc regs are 4 CONSECUTIVE s values
    // at fixed (h,hd) -> one packed 8B store. Vt[((b*16+h)*64+hd)*2048 + s].
#pragma unroll
    for (int nt = 0; nt < 4; ++nt) {
      int n = bn * 128 + wn * 64 + nt * 16 + col;
      float bvv = bias[n];
      int h = n >> 6, hd = n & 63;
#pragma unroll
      for (int mt = 0; mt < 4; ++mt) {
        int mbase = bm * 128 + wm * 64 + mt * 16 + quad * 4;
        int b = mbase >> 11, s = mbase & 2047;
        uint2 w;
        w.x = pkcvt(acc[mt][nt][0] + bvv, acc[mt][nt][1] + bvv);
        w.y = pkcvt(acc[mt][nt][2] + bvv, acc[mt][nt][3] + bvv);
        *(uint2*)(Ovt + ((size_t)((b * 16 + h) * 64 + hd)) * 2048 + s) = w;
      }
    }
  } else {
    u16* outB = z == 0 ? Oq : Ok;
#pragma unroll
    for (int nt = 0; nt < 4; ++nt) {
      int n = bn * 128 + wn * 64 + nt * 16 + col;
      float bvv = bias[n];
#pragma unroll
      for (int mt = 0; mt < 4; ++mt) {
        int mbase = bm * 128 + wm * 64 + mt * 16 + quad * 4;
#pragma unroll
        for (int reg = 0; reg < 4; ++reg) {
          int m = mbase + reg;
          float v = (acc[mt][nt][reg] + bvv) * scale;
          int b = m >> 11, s = m & 2047;
          int h = n >> 6, hd = n & 63;
          outB[((b * 16 + h) * 2048 + s) * 64 + hd] = f2bf(v);
        }
      }
    }
  }
}

// ---------------------------------------------------------------- out-proj GEMM (128x64 tile, fp32 out)
__global__ __launch_bounds__(256) void gemm_out(
    const u16* __restrict__ A, const u16* __restrict__ W,
    const float* __restrict__ bias, float* __restrict__ outF)
{
  constexpr int K = 1024;
  __shared__ u16 As[128 * 32];
  __shared__ u16 Bs[64 * 32];
  const int bm = blockIdx.x, bn = blockIdx.y;
  const int tid = threadIdx.x;
  const int lane = tid & 63, wave = tid >> 6;
  const int quad = lane >> 4, col = lane & 15;
  const int wm = wave >> 1, wn = wave & 1;

  const int L0 = tid, L1 = 256 + tid;
  const int r0 = L0 >> 2, c0 = (L0 & 3) ^ ((r0 >> 1) & 3);
  const int r1 = L1 >> 2, c1 = (L1 & 3) ^ ((r1 >> 1) & 3);
  const u16* gA0 = A + (bm * 128 + r0) * K + c0 * 8;
  const u16* gA1 = A + (bm * 128 + r1) * K + c1 * 8;
  const u16* gB0 = W + (bn * 64 + r0) * K + c0 * 8;   // Bs: 256 chunks, 1/thread
  u16* lA0 = As + L0 * 8; u16* lA1 = As + L1 * 8;
  u16* lB0 = Bs + L0 * 8;

  const int aRow = wm * 64 + col;
  const int bRow = wn * 32 + col;

  fx4 zero = {0.f, 0.f, 0.f, 0.f};
  fx4 acc[4][2];
#pragma unroll
  for (int i = 0; i < 4; ++i)
#pragma unroll
    for (int j = 0; j < 2; ++j) acc[i][j] = zero;

  for (int kb = 0; kb < K / 32; ++kb) {
    __syncthreads();
    g2l16(gA0 + kb * 32, lA0);
    g2l16(gA1 + kb * 32, lA1);
    g2l16(gB0 + kb * 32, lB0);
    __syncthreads();
    s16x8 af[4], bf[2];
#pragma unroll
    for (int mt = 0; mt < 4; ++mt) {
      int row = aRow + mt * 16;
      int ch = row * 4 + (quad ^ ((row >> 1) & 3));
      af[mt] = *(const s16x8*)(As + ch * 8);
    }
#pragma unroll
    for (int nt = 0; nt < 2; ++nt) {
      int row = bRow + nt * 16;
      int ch = row * 4 + (quad ^ ((row >> 1) & 3));
      bf[nt] = *(const s16x8*)(Bs + ch * 8);
    }
#pragma unroll
    for (int mt = 0; mt < 4; ++mt)
#pragma unroll
      for (int nt = 0; nt < 2; ++nt)
        acc[mt][nt] = __builtin_amdgcn_mfma_f32_16x16x32_bf16(af[mt], bf[nt], acc[mt][nt], 0, 0, 0);
  }

#pragma unroll
  for (int nt = 0; nt < 2; ++nt) {
    int n = bn * 64 + wn * 32 + nt * 16 + col;
    float bvv = bias[n];
#pragma unroll
    for (int mt = 0; mt < 4; ++mt) {
      int mbase = bm * 128 + wm * 64 + mt * 16 + quad * 4;
#pragma unroll
      for (int reg = 0; reg < 4; ++reg)
        outF[(mbase + reg) * 1024 + n] = acc[mt][nt][reg] + bvv;
    }
  }
}

// ---------------------------------------------------------------- flash attention
// grid (32 qt, 32 bh), 4 waves. Block: 64 q-rows x 128 kv per iter, 16 iters.
// Round-6 change: K is staged in LDS via global_load_lds (un-sinkable,
// register-free prefetch), one iteration ahead, single-buffered:
//   barrier A  (PV(i-1) done with Vs; K(i) staged block-wide)
//   issue V(i) staging (async, covered by QK^T)
//   QK^T reads K(i) from LDS (chunk-XOR swizzle: phys c = c ^ (d&7) via
//     pre-swizzled global source, linear dest -> ds_read 2-way = free)
//   vmcnt(0)  [drains own V(i)]  ; lgkmcnt(0) [P writes]
//   barrier B  (Vs staged block-wide; K(i) reads done block-wide)
//   issue K(i+1) staging into the now-free K buffer
//   PV MFMAs   (covers K(i+1) latency)
//   vmcnt(0)  [drains own K(i+1) before next barrier A]
// LDS 48KB (Vs 16K + Ks 16K + P 16K) -> 3 blocks/CU.
__global__ __launch_bounds__(256, 3) void flash_attn(
    const u16* __restrict__ Qp, const u16* __restrict__ Kp,
    const u16* __restrict__ Vt, u16* __restrict__ ctx)
{
  __shared__ u16 sh[24576];  // u16: Vs [0,8192) ; Ks [8192,16384) ; P [16384,24576)
  const int qt = blockIdx.x, bh = blockIdx.y;
  const int tid = threadIdx.x, lane = tid & 63, wave = tid >> 6;
  const int quad = lane >> 4, col = lane & 15;
  const int wm = wave >> 1, wn = wave & 1;

  const u16* Qb = Qp + ((size_t)bh * 2048 + qt * 64) * 64;
  const u16* Kb = Kp + (size_t)bh * 2048 * 64;
  const u16* Vb = Vt + (size_t)bh * 64 * 2048;

  s16x8 qf[2][2];   // B-operand: Q[m=lane&15][d=quad*8+j], halves of d=64
#pragma unroll
  for (int mt = 0; mt < 2; ++mt)
#pragma unroll
    for (int h = 0; h < 2; ++h)
      qf[mt][h] = *(const s16x8*)(Qb + (wm * 32 + mt * 16 + col) * 64 + h * 32 + quad * 8);

  fx4 zero = {0.f, 0.f, 0.f, 0.f};
  fx4 acc_o[2][4], acc_l[2];
#pragma unroll
  for (int mt = 0; mt < 2; ++mt) {
    acc_l[mt] = zero;
#pragma unroll
    for (int dt = 0; dt < 4; ++dt) acc_o[mt][dt] = zero;
  }
  s16x8 ones;
#pragma unroll
  for (int j = 0; j < 8; ++j) ones[j] = (short)0x3F80;  // bf16 1.0

  u16* Vs = sh;
  u16* Ks = sh + 8192;
  u16* Pw = sh + 16384 + wave * 2048;  // per-wave P[m=32][n=64], 16B-chunk swizzled

  // V-stage: per-lane PRE-SWIZZLED global source, linear LDS dest (rule-21 pair
  // with the PV read's `^ col`):  phys slot (d, p) holds V^T[d][p ^ (d&15)].
  const u16* vsrc[4];
#pragma unroll
  for (int i = 0; i < 4; ++i) {
    int d = wave * 16 + i * 4 + (lane >> 4);
    int cs = (lane & 15) ^ (d & 15);
    vsrc[i] = Vb + d * 2048 + cs * 8;
  }

  // K-stage: 128 rows x 8 chunks(16B) = 1024 chunks; thread covers 4.
  // phys chunk (d, c) holds logical chunk (c ^ (d&7)) of K row n0+d.
  // QK^T read of logical chunk L of row r: phys = L ^ (r&7)  -> banks spread,
  // 2 lanes/bank (free). Linear LDS dest as required by global_load_lds.
  const u16* ksrc[4];
  u16* kdst[4];
#pragma unroll
  for (int i = 0; i < 4; ++i) {
    int idx = wave * 256 + i * 64 + lane;
    int d = idx >> 3, c = idx & 7;
    ksrc[i] = Kb + d * 64 + (c ^ (d & 7)) * 8;
    kdst[i] = Ks + (wave * 256 + i * 64) * 8;   // wave-uniform base, +lane*16B by HW
  }

  // prologue: stage K(0), drain own loads, then loop-top barrier gives the
  // block-wide guarantee.
#pragma unroll
  for (int i = 0; i < 4; ++i) g2l16(ksrc[i], kdst[i]);
  asm volatile("s_waitcnt vmcnt(0)" ::: "memory");

  for (int kv = 0; kv < 16; ++kv) {
    const int n0 = kv * 128;
    __builtin_amdgcn_s_barrier();        // A: PV(i-1) done with Vs; K(i) staged
    // issue async V staging; latency hides under QK^T
#pragma unroll
    for (int i = 0; i < 4; ++i)
      g2l16(vsrc[i] + n0, Vs + (wave * 16 + i * 4) * 128);

    // scores S^T = K*Q^T, K from LDS; softmax; P write (b64)
    __builtin_amdgcn_s_setprio(1);
#pragma unroll
    for (int nt = 0; nt < 4; ++nt) {
      const int r = wn * 64 + nt * 16 + col;
      const u16* krow = Ks + r * 64;
      const int x = r & 7;
      s16x8 k0 = *(const s16x8*)(krow + ((quad ^ x) << 3));
      s16x8 k1 = *(const s16x8*)(krow + (((4 ^ quad) ^ x) << 3));
#pragma unroll
      for (int mt = 0; mt < 2; ++mt) {
        fx4 s = __builtin_amdgcn_mfma_f32_16x16x32_bf16(k0, qf[mt][0], zero, 0, 0, 0);
        s = __builtin_amdgcn_mfma_f32_16x16x32_bf16(k1, qf[mt][1], s, 0, 0, 0);
        int m = mt * 16 + col;
        int cch = 2 * nt + (quad >> 1);
        uint2 w;
        w.x = pkcvt(exp2f(s[0]), exp2f(s[1]));
        w.y = pkcvt(exp2f(s[2]), exp2f(s[3]));
        *(uint2*)(Pw + m * 64 + ((cch ^ (m & 7))) * 8 + (quad & 1) * 4) = w;
      }
    }
    __builtin_amdgcn_s_setprio(0);

    // V(i) landed (covered by QK^T); P ds_writes drained
    asm volatile("s_waitcnt vmcnt(0)" ::: "memory");
    asm volatile("s_waitcnt lgkmcnt(0)" ::: "memory");
    __builtin_amdgcn_s_barrier();        // B: Vs staged block-wide; K reads done

    // K buffer now free block-wide: issue K(i+1) staging (covered by PV)
    if (kv < 15) {
#pragma unroll
      for (int i = 0; i < 4; ++i)
        g2l16(ksrc[i] + (kv + 1) * 8192, kdst[i]);
    }

    // PV: A = P (own wave region), B = V^T rows; l via ones-MFMA
    __builtin_amdgcn_s_setprio(1);
#pragma unroll
    for (int ks = 0; ks < 2; ++ks) {
      s16x8 pf[2];
#pragma unroll
      for (int mt = 0; mt < 2; ++mt)
        pf[mt] = *(const s16x8*)(Pw + (mt * 16 + col) * 64 + ((4 * ks + quad) ^ (col & 7)) * 8);
#pragma unroll
      for (int dt = 0; dt < 4; ++dt) {
        s16x8 vf = *(const s16x8*)(Vs + (dt * 16 + col) * 128 + ((wn * 8 + 4 * ks + quad) ^ col) * 8);
#pragma unroll
        for (int mt = 0; mt < 2; ++mt)
          acc_o[mt][dt] = __builtin_amdgcn_mfma_f32_16x16x32_bf16(pf[mt], vf, acc_o[mt][dt], 0, 0, 0);
      }
#pragma unroll
      for (int mt = 0; mt < 2; ++mt)
        acc_l[mt] = __builtin_amdgcn_mfma_f32_16x16x32_bf16(pf[mt], ones, acc_l[mt], 0, 0, 0);
    }
    __builtin_amdgcn_s_setprio(0);

    // drain own K(i+1) before next barrier A (its cover was the PV phase)
    asm volatile("s_waitcnt vmcnt(0)" ::: "memory");
  }

  // cross-wave (wn) reduction of O,l partials via LDS, then epilogue by wn==0
  __syncthreads();
  float* buf = (float*)sh;
  if (wn == 1) {
#pragma unroll
    for (int mt = 0; mt < 2; ++mt) {
#pragma unroll
      for (int dt = 0; dt < 4; ++dt)
#pragma unroll
        for (int e = 0; e < 4; ++e)
          buf[wm * 2560 + ((mt * 4 + dt) * 4 + e) * 64 + lane] = acc_o[mt][dt][e];
#pragma unroll
      for (int e = 0; e < 4; ++e)
        buf[wm * 2560 + (32 + mt * 4 + e) * 64 + lane] = acc_l[mt][e];
    }
  }
  __syncthreads();
  if (wn == 0) {
    const int b = bh >> 4, h = bh & 15;
#pragma unroll
    for (int mt = 0; mt < 2; ++mt) {
      fx4 rl;
#pragma unroll
      for (int e = 0; e < 4; ++e) {
        float l = acc_l[mt][e] + buf[wm * 2560 + (32 + mt * 4 + e) * 64 + lane];
        rl[e] = 1.0f / l;
      }
#pragma unroll
      for (int dt = 0; dt < 4; ++dt)
#pragma unroll
        for (int e = 0; e < 4; ++e) {
          float v = (acc_o[mt][dt][e] + buf[wm * 2560 + ((mt * 4 + dt) * 4 + e) * 64 + lane]) * rl[e];
          int s = qt * 64 + wm * 32 + mt * 16 + quad * 4 + e;
          ctx[((size_t)(b * 2048 + s)) * 1024 + h * 64 + dt * 16 + col] = f2bf(v);
        }
    }
  }
}

// ---------------------------------------------------------------- launch
extern "C" void kernel_launch(void* const* d_in, const int* in_sizes, int n_in,
                              void* d_out, int out_size, void* d_ws, size_t ws_size,
                              hipStream_t stream) {
  const float* q  = (const float*)d_in[0];
  const float* k  = (const float*)d_in[1];
  const float* v  = (const float*)d_in[2];
  const float* Wq = (const float*)d_in[3];
  const float* bq = (const float*)d_in[4];
  const float* Wk = (const float*)d_in[5];
  const float* bk = (const float*)d_in[6];
  const float* Wv = (const float*)d_in[7];
  const float* bv = (const float*)d_in[8];
  const float* Wo = (const float*)d_in[9];
  const float* bo = (const float*)d_in[10];
  float* out = (float*)d_out;

  char* ws = (char*)d_ws;
  const size_t MB = 1u << 20;
  u16* qb  = (u16*)(ws + 0 * MB);
  u16* kb  = (u16*)(ws + 8 * MB);
  u16* vb  = (u16*)(ws + 16 * MB);
  u16* wqb = (u16*)(ws + 24 * MB);
  u16* wkb = (u16*)(ws + 26 * MB);
  u16* wvb = (u16*)(ws + 28 * MB);
  u16* wob = (u16*)(ws + 30 * MB);
  u16* Qp  = (u16*)(ws + 32 * MB);
  u16* Kp  = (u16*)(ws + 40 * MB);
  u16* Vtp = (u16*)(ws + 56 * MB);
  u16* ctx = (u16*)(ws + 64 * MB);   // total 72 MB

  cvt3<<<dim3(4096, 3), 256, 0, stream>>>(q, k, v, qb, kb, vb, 1048576);
  cvt4<<<dim3(1024, 4), 256, 0, stream>>>(Wq, Wk, Wv, Wo, wqb, wkb, wvb, wob, 262144);

  gemm_qkv<<<dim3(32, 8, 3), 256, 0, stream>>>(qb, kb, vb, wqb, wkb, wvb,
                                               bq, bk, bv, Qp, Kp, Vtp);
  flash_attn<<<dim3(32, 32), 256, 0, stream>>>(Qp, Kp, Vtp, ctx);
  gemm_out<<<dim3(32, 16), 256, 0, stream>>>(ctx, wob, bo, out);
}

// Round 8
// 221.069 us; speedup vs baseline: 1.1749x; 1.0524x over previous
//
#include <hip/hip_runtime.h>
#include <stdint.h>

typedef unsigned short u16;
typedef unsigned int u32;
typedef __attribute__((ext_vector_type(8))) short s16x8;   // 8 bf16 (4 VGPRs)
typedef __attribute__((ext_vector_type(4))) float fx4;     // 4 fp32 acc

#define AS_GLOBAL __attribute__((address_space(1)))
#define AS_LDS    __attribute__((address_space(3)))

__device__ __forceinline__ void g2l16(const u16* g, u16* l) {
  __builtin_amdgcn_global_load_lds((const AS_GLOBAL unsigned int*)g,
                                   (AS_LDS unsigned int*)l, 16, 0, 0);
}
__device__ __forceinline__ u16 f2bf(float f) {   // fp32 -> bf16 RNE
  u32 u = __float_as_uint(f);
  u += 0x7FFF + ((u >> 16) & 1);
  return (u16)(u >> 16);
}
// hardware packed fp32->bf16 RNE (1 VOP3 for 2 elements)
__device__ __forceinline__ u32 pkcvt(float a, float b) {
  u32 r;
  asm("v_cvt_pk_bf16_f32 %0, %1, %2" : "=v"(r) : "v"(a), "v"(b));
  return r;
}

// ---------------------------------------------------------------- converts (fused)
__global__ __launch_bounds__(256) void cvt3(const float* __restrict__ a, const float* __restrict__ b,
                                            const float* __restrict__ c, u16* oa, u16* ob, u16* oc, int n4) {
  const float* src = blockIdx.y == 0 ? a : blockIdx.y == 1 ? b : c;
  u16* dst = blockIdx.y == 0 ? oa : blockIdx.y == 1 ? ob : oc;
  int i = blockIdx.x * 256 + threadIdx.x;
  if (i >= n4) return;
  float4 f = ((const float4*)src)[i];
  ushort4 o; o.x = f2bf(f.x); o.y = f2bf(f.y); o.z = f2bf(f.z); o.w = f2bf(f.w);
  ((ushort4*)dst)[i] = o;
}
__global__ __launch_bounds__(256) void cvt4(const float* __restrict__ a, const float* __restrict__ b,
                                            const float* __restrict__ c, const float* __restrict__ d,
                                            u16* oa, u16* ob, u16* oc, u16* od, int n4) {
  const float* src = blockIdx.y == 0 ? a : blockIdx.y == 1 ? b : blockIdx.y == 2 ? c : d;
  u16* dst = blockIdx.y == 0 ? oa : blockIdx.y == 1 ? ob : blockIdx.y == 2 ? oc : od;
  int i = blockIdx.x * 256 + threadIdx.x;
  if (i >= n4) return;
  float4 f = ((const float4*)src)[i];
  ushort4 o; o.x = f2bf(f.x); o.y = f2bf(f.y); o.z = f2bf(f.z); o.w = f2bf(f.w);
  ((ushort4*)dst)[i] = o;
}

// ---------------------------------------------------------------- fused QKV GEMM
// z==0 (Q): scaled by sm_scale*log2e, layout [B,H,S,Hd].
// z==1 (K): layout [B,H,S,Hd].
// z==2 (V): written DIRECTLY as V^T [B,H,Hd,S] (transpose_v kernel eliminated).
__global__ __launch_bounds__(256) void gemm_qkv(
    const u16* __restrict__ Aq, const u16* __restrict__ Ak, const u16* __restrict__ Av,
    const u16* __restrict__ Wq, const u16* __restrict__ Wk, const u16* __restrict__ Wv,
    const float* __restrict__ bq, const float* __restrict__ bk, const float* __restrict__ bv,
    u16* __restrict__ Oq, u16* __restrict__ Ok, u16* __restrict__ Ovt)
{
  constexpr int K = 1024;
  __shared__ u16 As[128 * 32];
  __shared__ u16 Bs[128 * 32];
  const int z = blockIdx.z;
  const u16* A = z == 0 ? Aq : z == 1 ? Ak : Av;
  const u16* W = z == 0 ? Wq : z == 1 ? Wk : Wv;
  const float* bias = z == 0 ? bq : z == 1 ? bk : bv;
  const float scale = z == 0 ? 0.180336880f : 1.0f;  // 0.125 * log2(e)

  const int bm = blockIdx.x, bn = blockIdx.y;
  const int tid = threadIdx.x;
  const int lane = tid & 63, wave = tid >> 6;
  const int quad = lane >> 4, col = lane & 15;
  const int wm = wave >> 1, wn = wave & 1;

  const int L0 = tid, L1 = 256 + tid;
  const int r0 = L0 >> 2, c0 = (L0 & 3) ^ ((r0 >> 1) & 3);
  const int r1 = L1 >> 2, c1 = (L1 & 3) ^ ((r1 >> 1) & 3);
  const u16* gA0 = A + (bm * 128 + r0) * K + c0 * 8;
  const u16* gA1 = A + (bm * 128 + r1) * K + c1 * 8;
  const u16* gB0 = W + (bn * 128 + r0) * K + c0 * 8;
  const u16* gB1 = W + (bn * 128 + r1) * K + c1 * 8;
  u16* lA0 = As + L0 * 8; u16* lA1 = As + L1 * 8;
  u16* lB0 = Bs + L0 * 8; u16* lB1 = Bs + L1 * 8;

  const int aRow = wm * 64 + col;
  const int bRow = wn * 64 + col;

  fx4 zero = {0.f, 0.f, 0.f, 0.f};
  fx4 acc[4][4];
#pragma unroll
  for (int i = 0; i < 4; ++i)
#pragma unroll
    for (int j = 0; j < 4; ++j) acc[i][j] = zero;

  for (int kb = 0; kb < K / 32; ++kb) {
    __syncthreads();
    g2l16(gA0 + kb * 32, lA0);
    g2l16(gA1 + kb * 32, lA1);
    g2l16(gB0 + kb * 32, lB0);
    g2l16(gB1 + kb * 32, lB1);
    __syncthreads();
    s16x8 af[4], bf[4];
#pragma unroll
    for (int mt = 0; mt < 4; ++mt) {
      int row = aRow + mt * 16;
      int ch = row * 4 + (quad ^ ((row >> 1) & 3));
      af[mt] = *(const s16x8*)(As + ch * 8);
    }
#pragma unroll
    for (int nt = 0; nt < 4; ++nt) {
      int row = bRow + nt * 16;
      int ch = row * 4 + (quad ^ ((row >> 1) & 3));
      bf[nt] = *(const s16x8*)(Bs + ch * 8);
    }
#pragma unroll
    for (int mt = 0; mt < 4; ++mt)
#pragma unroll
      for (int nt = 0; nt < 4; ++nt)
        acc[mt][nt] = __builtin_amdgcn_mfma_f32_16x16x32_bf16(af[mt], bf[nt], acc[mt][nt], 0, 0, 0);
  }

  if (z == 2) {
    // direct V^T store: per (mt,nt) the 4 acc regs are 4 CONSECUTIVE s values
    // at fixed (h,hd) -> one packed 8B store. Vt[((b*16+h)*64+hd)*2048 + s].
#pragma unroll
    for (int nt = 0; nt < 4; ++nt) {
      int n = bn * 128 + wn * 64 + nt * 16 + col;
      float bvv = bias[n];
      int h = n >> 6, hd = n & 63;
#pragma unroll
      for (int mt = 0; mt < 4; ++mt) {
        int mbase = bm * 128 + wm * 64 + mt * 16 + quad * 4;
        int b = mbase >> 11, s = mbase & 2047;
        uint2 w;
        w.x = pkcvt(acc[mt][nt][0] + bvv, acc[mt][nt][1] + bvv);
        w.y = pkcvt(acc[mt][nt][2] + bvv, acc[mt][nt][3] + bvv);
        *(uint2*)(Ovt + ((size_t)((b * 16 + h) * 64 + hd)) * 2048 + s) = w;
      }
    }
  } else {
    u16* outB = z == 0 ? Oq : Ok;
#pragma unroll
    for (int nt = 0; nt < 4; ++nt) {
      int n = bn * 128 + wn * 64 + nt * 16 + col;
      float bvv = bias[n];
#pragma unroll
      for (int mt = 0; mt < 4; ++mt) {
        int mbase = bm * 128 + wm * 64 + mt * 16 + quad * 4;
#pragma unroll
        for (int reg = 0; reg < 4; ++reg) {
          int m = mbase + reg;
          float v = (acc[mt][nt][reg] + bvv) * scale;
          int b = m >> 11, s = m & 2047;
          int h = n >> 6, hd = n & 63;
          outB[((b * 16 + h) * 2048 + s) * 64 + hd] = f2bf(v);
        }
      }
    }
  }
}

// ---------------------------------------------------------------- out-proj GEMM (128x64 tile, fp32 out)
__global__ __launch_bounds__(256) void gemm_out(
    const u16* __restrict__ A, const u16* __restrict__ W,
    const float* __restrict__ bias, float* __restrict__ outF)
{
  constexpr int K = 1024;
  __shared__ u16 As[128 * 32];
  __shared__ u16 Bs[64 * 32];
  const int bm = blockIdx.x, bn = blockIdx.y;
  const int tid = threadIdx.x;
  const int lane = tid & 63, wave = tid >> 6;
  const int quad = lane >> 4, col = lane & 15;
  const int wm = wave >> 1, wn = wave & 1;

  const int L0 = tid, L1 = 256 + tid;
  const int r0 = L0 >> 2, c0 = (L0 & 3) ^ ((r0 >> 1) & 3);
  const int r1 = L1 >> 2, c1 = (L1 & 3) ^ ((r1 >> 1) & 3);
  const u16* gA0 = A + (bm * 128 + r0) * K + c0 * 8;
  const u16* gA1 = A + (bm * 128 + r1) * K + c1 * 8;
  const u16* gB0 = W + (bn * 64 + r0) * K + c0 * 8;   // Bs: 256 chunks, 1/thread
  u16* lA0 = As + L0 * 8; u16* lA1 = As + L1 * 8;
  u16* lB0 = Bs + L0 * 8;

  const int aRow = wm * 64 + col;
  const int bRow = wn * 32 + col;

  fx4 zero = {0.f, 0.f, 0.f, 0.f};
  fx4 acc[4][2];
#pragma unroll
  for (int i = 0; i < 4; ++i)
#pragma unroll
    for (int j = 0; j < 2; ++j) acc[i][j] = zero;

  for (int kb = 0; kb < K / 32; ++kb) {
    __syncthreads();
    g2l16(gA0 + kb * 32, lA0);
    g2l16(gA1 + kb * 32, lA1);
    g2l16(gB0 + kb * 32, lB0);
    __syncthreads();
    s16x8 af[4], bf[2];
#pragma unroll
    for (int mt = 0; mt < 4; ++mt) {
      int row = aRow + mt * 16;
      int ch = row * 4 + (quad ^ ((row >> 1) & 3));
      af[mt] = *(const s16x8*)(As + ch * 8);
    }
#pragma unroll
    for (int nt = 0; nt < 2; ++nt) {
      int row = bRow + nt * 16;
      int ch = row * 4 + (quad ^ ((row >> 1) & 3));
      bf[nt] = *(const s16x8*)(Bs + ch * 8);
    }
#pragma unroll
    for (int mt = 0; mt < 4; ++mt)
#pragma unroll
      for (int nt = 0; nt < 2; ++nt)
        acc[mt][nt] = __builtin_amdgcn_mfma_f32_16x16x32_bf16(af[mt], bf[nt], acc[mt][nt], 0, 0, 0);
  }

#pragma unroll
  for (int nt = 0; nt < 2; ++nt) {
    int n = bn * 64 + wn * 32 + nt * 16 + col;
    float bvv = bias[n];
#pragma unroll
    for (int mt = 0; mt < 4; ++mt) {
      int mbase = bm * 128 + wm * 64 + mt * 16 + quad * 4;
#pragma unroll
      for (int reg = 0; reg < 4; ++reg)
        outF[(mbase + reg) * 1024 + n] = acc[mt][nt][reg] + bvv;
    }
  }
}

// ---------------------------------------------------------------- flash attention
// Round-8: QBLK 64 -> 128, 8 waves (512 thr). grid (16 qt, 32 bh).
// Same per-wave inner schedule as the round-7 PASS (K LDS-staged, single-buffered,
// prefetched one iter ahead); only the wave decomposition changes:
//   waves: wm = wave>>1 (0..3) -> q-slice of 32 rows;  wn = wave&1 -> kv half.
// Rationale: compute per staged K/V byte doubles; per-thread staging issue
// halves; K/V re-fetch per bh halves (16 blocks vs 32); occupancy 2 blocks/CU
// x 8 waves = 16 waves/CU (vs measured 22% ~= 7).
// LDS 64KB: Vs 16K + Ks 16K + P 8x4K = 32768 u16.
__global__ __launch_bounds__(512, 4) void flash_attn(
    const u16* __restrict__ Qp, const u16* __restrict__ Kp,
    const u16* __restrict__ Vt, u16* __restrict__ ctx)
{
  __shared__ u16 sh[32768];  // u16: Vs [0,8192) ; Ks [8192,16384) ; P [16384,32768)
  const int qt = blockIdx.x, bh = blockIdx.y;
  const int tid = threadIdx.x, lane = tid & 63, wave = tid >> 6;
  const int quad = lane >> 4, col = lane & 15;
  const int wm = wave >> 1, wn = wave & 1;

  const u16* Qb = Qp + ((size_t)bh * 2048 + qt * 128) * 64;
  const u16* Kb = Kp + (size_t)bh * 2048 * 64;
  const u16* Vb = Vt + (size_t)bh * 64 * 2048;

  s16x8 qf[2][2];   // B-operand: Q[m=lane&15][d=quad*8+j], halves of d=64
#pragma unroll
  for (int mt = 0; mt < 2; ++mt)
#pragma unroll
    for (int h = 0; h < 2; ++h)
      qf[mt][h] = *(const s16x8*)(Qb + (wm * 32 + mt * 16 + col) * 64 + h * 32 + quad * 8);

  fx4 zero = {0.f, 0.f, 0.f, 0.f};
  fx4 acc_o[2][4], acc_l[2];
#pragma unroll
  for (int mt = 0; mt < 2; ++mt) {
    acc_l[mt] = zero;
#pragma unroll
    for (int dt = 0; dt < 4; ++dt) acc_o[mt][dt] = zero;
  }
  s16x8 ones;
#pragma unroll
  for (int j = 0; j < 8; ++j) ones[j] = (short)0x3F80;  // bf16 1.0

  u16* Vs = sh;
  u16* Ks = sh + 8192;
  u16* Pw = sh + 16384 + wave * 2048;  // per-wave P[m=32][n=64], 16B-chunk swizzled

  // V-stage: 1024 chunks (64 d x 16 c), 512 threads -> 2 each. PRE-SWIZZLED
  // global source, linear LDS dest: phys slot (d, p) holds V^T[d][p ^ (d&15)].
  const u16* vsrc[2];
#pragma unroll
  for (int i = 0; i < 2; ++i) {
    int d = wave * 8 + i * 4 + (lane >> 4);
    int cs = (lane & 15) ^ (d & 15);
    vsrc[i] = Vb + d * 2048 + cs * 8;
  }

  // K-stage: 1024 chunks (128 rows x 8 chunks), 2 per thread.
  // phys chunk (d, c) holds logical chunk (c ^ (d&7)) of K row n0+d.
  const u16* ksrc[2];
  u16* kdst[2];
#pragma unroll
  for (int i = 0; i < 2; ++i) {
    int idx = wave * 128 + i * 64 + lane;
    int d = idx >> 3, c = idx & 7;
    ksrc[i] = Kb + d * 64 + (c ^ (d & 7)) * 8;
    kdst[i] = Ks + (wave * 128 + i * 64) * 8;   // wave-uniform base, +lane*16B by HW
  }

  // prologue: stage K(0), drain own loads; loop-top barrier = block guarantee.
#pragma unroll
  for (int i = 0; i < 2; ++i) g2l16(ksrc[i], kdst[i]);
  asm volatile("s_waitcnt vmcnt(0)" ::: "memory");

  for (int kv = 0; kv < 16; ++kv) {
    const int n0 = kv * 128;
    __builtin_amdgcn_s_barrier();        // A: PV(i-1) done with Vs; K(i) staged
    // issue async V staging; latency hides under QK^T
#pragma unroll
    for (int i = 0; i < 2; ++i)
      g2l16(vsrc[i] + n0, Vs + (wave * 8 + i * 4) * 128);

    // scores S^T = K*Q^T, K from LDS; softmax; P write (b64)
    __builtin_amdgcn_s_setprio(1);
#pragma unroll
    for (int nt = 0; nt < 4; ++nt) {
      const int r = wn * 64 + nt * 16 + col;
      const u16* krow = Ks + r * 64;
      const int x = r & 7;
      s16x8 k0 = *(const s16x8*)(krow + ((quad ^ x) << 3));
      s16x8 k1 = *(const s16x8*)(krow + (((4 ^ quad) ^ x) << 3));
#pragma unroll
      for (int mt = 0; mt < 2; ++mt) {
        fx4 s = __builtin_amdgcn_mfma_f32_16x16x32_bf16(k0, qf[mt][0], zero, 0, 0, 0);
        s = __builtin_amdgcn_mfma_f32_16x16x32_bf16(k1, qf[mt][1], s, 0, 0, 0);
        int m = mt * 16 + col;
        int cch = 2 * nt + (quad >> 1);
        uint2 w;
        w.x = pkcvt(exp2f(s[0]), exp2f(s[1]));
        w.y = pkcvt(exp2f(s[2]), exp2f(s[3]));
        *(uint2*)(Pw + m * 64 + ((cch ^ (m & 7))) * 8 + (quad & 1) * 4) = w;
      }
    }
    __builtin_amdgcn_s_setprio(0);

    // V(i) landed (covered by QK^T); P ds_writes drained
    asm volatile("s_waitcnt vmcnt(0)" ::: "memory");
    asm volatile("s_waitcnt lgkmcnt(0)" ::: "memory");
    __builtin_amdgcn_s_barrier();        // B: Vs staged block-wide; K reads done

    // K buffer now free block-wide: issue K(i+1) staging (covered by PV)
    if (kv < 15) {
#pragma unroll
      for (int i = 0; i < 2; ++i)
        g2l16(ksrc[i] + (kv + 1) * 8192, kdst[i]);
    }

    // PV: A = P (own wave region), B = V^T rows; l via ones-MFMA
    __builtin_amdgcn_s_setprio(1);
#pragma unroll
    for (int ks = 0; ks < 2; ++ks) {
      s16x8 pf[2];
#pragma unroll
      for (int mt = 0; mt < 2; ++mt)
        pf[mt] = *(const s16x8*)(Pw + (mt * 16 + col) * 64 + ((4 * ks + quad) ^ (col & 7)) * 8);
#pragma unroll
      for (int dt = 0; dt < 4; ++dt) {
        s16x8 vf = *(const s16x8*)(Vs + (dt * 16 + col) * 128 + ((wn * 8 + 4 * ks + quad) ^ col) * 8);
#pragma unroll
        for (int mt = 0; mt < 2; ++mt)
          acc_o[mt][dt] = __builtin_amdgcn_mfma_f32_16x16x32_bf16(pf[mt], vf, acc_o[mt][dt], 0, 0, 0);
      }
#pragma unroll
      for (int mt = 0; mt < 2; ++mt)
        acc_l[mt] = __builtin_amdgcn_mfma_f32_16x16x32_bf16(pf[mt], ones, acc_l[mt], 0, 0, 0);
    }
    __builtin_amdgcn_s_setprio(0);

    // drain own K(i+1) before next barrier A (its cover was the PV phase)
    asm volatile("s_waitcnt vmcnt(0)" ::: "memory");
  }

  // cross-wave (wn) reduction of O,l partials via LDS, then epilogue by wn==0
  __syncthreads();
  float* buf = (float*)sh;
  if (wn == 1) {
#pragma unroll
    for (int mt = 0; mt < 2; ++mt) {
#pragma unroll
      for (int dt = 0; dt < 4; ++dt)
#pragma unroll
        for (int e = 0; e < 4; ++e)
          buf[wm * 2560 + ((mt * 4 + dt) * 4 + e) * 64 + lane] = acc_o[mt][dt][e];
#pragma unroll
      for (int e = 0; e < 4; ++e)
        buf[wm * 2560 + (32 + mt * 4 + e) * 64 + lane] = acc_l[mt][e];
    }
  }
  __syncthreads();
  if (wn == 0) {
    const int b = bh >> 4, h = bh & 15;
#pragma unroll
    for (int mt = 0; mt < 2; ++mt) {
      fx4 rl;
#pragma unroll
      for (int e = 0; e < 4; ++e) {
        float l = acc_l[mt][e] + buf[wm * 2560 + (32 + mt * 4 + e) * 64 + lane];
        rl[e] = 1.0f / l;
      }
#pragma unroll
      for (int dt = 0; dt < 4; ++dt)
#pragma unroll
        for (int e = 0; e < 4; ++e) {
          float v = (acc_o[mt][dt][e] + buf[wm * 2560 + ((mt * 4 + dt) * 4 + e) * 64 + lane]) * rl[e];
          int s = qt * 128 + wm * 32 + mt * 16 + quad * 4 + e;
          ctx[((size_t)(b * 2048 + s)) * 1024 + h * 64 + dt * 16 + col] = f2bf(v);
        }
    }
  }
}

// ---------------------------------------------------------------- launch
extern "C" void kernel_launch(void* const* d_in, const int* in_sizes, int n_in,
                              void* d_out, int out_size, void* d_ws, size_t ws_size,
                              hipStream_t stream) {
  const float* q  = (const float*)d_in[0];
  const float* k  = (const float*)d_in[1];
  const float* v  = (const float*)d_in[2];
  const float* Wq = (const float*)d_in[3];
  const float* bq = (const float*)d_in[4];
  const float* Wk = (const float*)d_in[5];
  const float* bk = (const float*)d_in[6];
  const float* Wv = (const float*)d_in[7];
  const float* bv = (const float*)d_in[8];
  const float* Wo = (const float*)d_in[9];
  const float* bo = (const float*)d_in[10];
  float* out = (float*)d_out;

  char* ws = (char*)d_ws;
  const size_t MB = 1u << 20;
  u16* qb  = (u16*)(ws + 0 * MB);
  u16* kb  = (u16*)(ws + 8 * MB);
  u16* vb  = (u16*)(ws + 16 * MB);
  u16* wqb = (u16*)(ws + 24 * MB);
  u16* wkb = (u16*)(ws + 26 * MB);
  u16* wvb = (u16*)(ws + 28 * MB);
  u16* wob = (u16*)(ws + 30 * MB);
  u16* Qp  = (u16*)(ws + 32 * MB);
  u16* Kp  = (u16*)(ws + 40 * MB);
  u16* Vtp = (u16*)(ws + 56 * MB);
  u16* ctx = (u16*)(ws + 64 * MB);   // total 72 MB

  cvt3<<<dim3(4096, 3), 256, 0, stream>>>(q, k, v, qb, kb, vb, 1048576);
  cvt4<<<dim3(1024, 4), 256, 0, stream>>>(Wq, Wk, Wv, Wo, wqb, wkb, wvb, wob, 262144);

  gemm_qkv<<<dim3(32, 8, 3), 256, 0, stream>>>(qb, kb, vb, wqb, wkb, wvb,
                                               bq, bk, bv, Qp, Kp, Vtp);
  flash_attn<<<dim3(16, 32), 512, 0, stream>>>(Qp, Kp, Vtp, ctx);
  gemm_out<<<dim3(32, 16), 256, 0, stream>>>(ctx, wob, bo, out);
}